// Round 11
// baseline (190.591 us; speedup 1.0000x reference)
//
#include <hip/hip_runtime.h>
#include <hip/hip_bf16.h>
#include <math.h>

#define B_TOT 8192
#define OBS   4096
#define NG    4
#define GSZ   1024
#define LATD  64
#define HDIM  128

typedef __attribute__((ext_vector_type(8))) short   short8_t;
typedef __attribute__((ext_vector_type(8))) unsigned short ushort8_t;
typedef __attribute__((ext_vector_type(4))) float   float4_t;

__constant__ int kMask[15] = {1,2,4,8, 3,5,9,6,10,12, 7,11,13,14, 15};

static __device__ __forceinline__ unsigned short f2b(float x) {
  __hip_bfloat16 b = __float2bfloat16(x);
  return *reinterpret_cast<unsigned short*>(&b);
}
static __device__ __forceinline__ unsigned int pack2(float lo, float hi) {
  return (unsigned int)f2b(lo) | ((unsigned int)f2b(hi) << 16);
}

// ------------- weight prep: bf16 + fragment-panel layouts (verified R9) ----
// Panel slab = 512 shorts [l15][oct][j]; wave B-load = 64 lanes x 16B contig.
// Strides (shorts): W1p: ni 512, ks 1024, (g,q) 32768
//                   W2p: ni 512, ks 4096, g 16384
//                   W3p: ni 512, ks 2048, g 4096
//                   W4p: ni 512, ks 1024, oh 2048, ob 4096, g 65536
#define N1 524288
#define N2 65536
#define N3 16384
#define N4 262144
__global__ __launch_bounds__(256) void k_prep(const float* __restrict__ w1,
                                              const float* __restrict__ w2,
                                              const float* __restrict__ w3,
                                              const float* __restrict__ w4,
                                              unsigned short* __restrict__ W1p,
                                              unsigned short* __restrict__ W2p,
                                              unsigned short* __restrict__ W3p,
                                              unsigned short* __restrict__ W4p) {
  const int i = blockIdx.x * 256 + threadIdx.x;
  if (i < N1) {
    const int j = i & 7, oct = (i >> 3) & 3, l15 = (i >> 5) & 15;
    const int ni = (i >> 9) & 1, ks = (i >> 10) & 31;
    const int w = (i >> 15) & 3, g = (i >> 17) & 3;
    const int k = ks * 32 + oct * 8 + j;
    const int h = w * 32 + ni * 16 + l15;
    W1p[i] = f2b(w1[g * 131072 + k * 128 + h]);
  } else if (i < N1 + N2) {
    const int idx = i - N1;
    const int j = idx & 7, oct = (idx >> 3) & 3, l15 = (idx >> 5) & 15;
    const int ni = (idx >> 9) & 7, ks = (idx >> 12) & 3, g = (idx >> 14) & 3;
    const int k = ks * 32 + oct * 8 + j;
    const int col = ni * 16 + l15;
    W2p[idx] = f2b(w2[g * 16384 + k * 128 + col]);
  } else if (i < N1 + N2 + N3) {
    const int idx = i - N1 - N2;
    const int j = idx & 7, oct = (idx >> 3) & 3, l15 = (idx >> 5) & 15;
    const int ni = (idx >> 9) & 3, ks = (idx >> 11) & 1, g = (idx >> 12) & 3;
    const int k = ks * 32 + oct * 8 + j;
    const int m = ni * 16 + l15;
    W3p[idx] = f2b(w3[g * 4096 + k * 64 + m]);
  } else if (i < N1 + N2 + N3 + N4) {
    const int idx = i - N1 - N2 - N3;
    const int j = idx & 7, oct = (idx >> 3) & 3, l15 = (idx >> 5) & 15;
    const int ni = (idx >> 9) & 1, ks = (idx >> 10) & 1;
    const int oh = (idx >> 11) & 1, ob = (idx >> 12) & 15, g = (idx >> 16) & 3;
    const int k = ks * 32 + oct * 8 + j;
    const int o = ob * 64 + oh * 32 + ni * 16 + l15;
    W4p[idx] = f2b(w4[g * 65536 + k * 1024 + o]);
  }
}

// ---------------- X de-interleave: Xt[b][g][k] = bf16(X[b][4k+g]) ----------
// (verified R7) 4096 blocks x 512 thr.
__global__ __launch_bounds__(512) void k_prepx(const float* __restrict__ X,
                                               unsigned short* __restrict__ Xt) {
  const int t = threadIdx.x;
  const int b = blockIdx.x * 2 + (t >> 8);
  const int t256 = t & 255;
  const float* p = X + (size_t)b * OBS + t256 * 16;
  const float4_t f0 = *(const float4_t*)(p);
  const float4_t f1 = *(const float4_t*)(p + 4);
  const float4_t f2 = *(const float4_t*)(p + 8);
  const float4_t f3 = *(const float4_t*)(p + 12);
  const int k0 = t256 * 4;
  unsigned short* q = Xt + (size_t)b * OBS;
#pragma unroll
  for (int g = 0; g < 4; ++g) {
    uint2 v;
    v.x = pack2(f0[g], f1[g]);
    v.y = pack2(f2[g], f3[g]);
    *(uint2*)(q + g * GSZ + k0) = v;
  }
}

// -------- enc1 split-K GEMM, dec2-clone: S[half] += Xg @ W1 ---------------
// grid (256 rtile, 8 colblk, 2 half) = 4096 blocks x 256 thr. NO LDS, NO
// barriers. Wave tile 32r x 16c; K=512 per half, 16 ksteps; all fragment
// loads direct-global (A strided 16B/lane like dec2's Hd; B 1KB panels, L2).
__global__ __launch_bounds__(256) void k_enc1s(const unsigned short* __restrict__ Xt,
                                               const unsigned short* __restrict__ W1p,
                                               float* __restrict__ S) {
  const int tid = threadIdx.x;
  const int w   = tid >> 6;
  const int l   = tid & 63;
  const int l15 = l & 15;
  const int oct = l >> 4;
  const int rb  = blockIdx.x * 32;
  const int by  = blockIdx.y;           // 0..7
  const int g   = by >> 1;
  const int q   = (by & 1) * 2 + (w >> 1);   // col quarter 0..3
  const int ni  = w & 1;
  const int half = blockIdx.z;

  const unsigned short* abase = Xt + (size_t)(rb + l15) * OBS + g * GSZ +
                                half * 512 + oct * 8;
  const unsigned short* bbase = W1p + (size_t)(g * 4 + q) * 32768 +
                                (half * 16) * 1024 + ni * 512 +
                                (l15 * 4 + oct) * 8;

  float4_t acc[2];
  acc[0] = (float4_t){0.f, 0.f, 0.f, 0.f};
  acc[1] = (float4_t){0.f, 0.f, 0.f, 0.f};

#pragma unroll
  for (int ks = 0; ks < 16; ++ks) {
    const short8_t af0 = *(const short8_t*)(abase + ks * 32);
    const short8_t af1 = *(const short8_t*)(abase + (size_t)16 * OBS + ks * 32);
    const short8_t bf  = *(const short8_t*)(bbase + ks * 1024);
    acc[0] = __builtin_amdgcn_mfma_f32_16x16x32_bf16(af0, bf, acc[0], 0, 0, 0);
    acc[1] = __builtin_amdgcn_mfma_f32_16x16x32_bf16(af1, bf, acc[1], 0, 0, 0);
  }

  const int col = g * 128 + q * 32 + ni * 16 + l15;
  float* sp = S + (size_t)half * B_TOT * 512;
#pragma unroll
  for (int mi = 0; mi < 2; ++mi)
#pragma unroll
    for (int j = 0; j < 4; ++j)
      sp[(size_t)(rb + mi * 16 + oct * 4 + j) * 512 + col] = acc[mi][j];
}

// -------- samp2: h=relu(S0+S1+b1) -> enc2 -> PoE/sample -> dec1 -> Hd ------
// 512 blocks x 256 thr (4 waves; wave = group). Block = 16 batch rows.
// h and z stored in LDS in FRAGMENT-PANEL order (lane*16B slabs, conflict-
// free by construction); B operands direct-global panels (L2-hot).
__global__ __launch_bounds__(256, 3) void k_samp2(const float* __restrict__ S,
                                                  const unsigned short* __restrict__ W2p,
                                                  const unsigned short* __restrict__ W3p,
                                                  const float* __restrict__ B1,
                                                  const float* __restrict__ B2,
                                                  const float* __restrict__ DB1,
                                                  const float* __restrict__ eps,
                                                  const int*   __restrict__ subset_idx,
                                                  unsigned short* __restrict__ Hd) {
  __shared__ __align__(16) unsigned short hpan[16 * 512];   // 16 slabs x 1KB
  __shared__ __align__(16) float mls[16 * 516];             // 33 KB
  __shared__ __align__(16) unsigned short zbp[2 * 512];     // 2 slabs

  const int tid = threadIdx.x;
  const int g   = tid >> 6;
  const int l   = tid & 63;
  const int l15 = l & 15;
  const int oct = l >> 4;
  const int rb  = blockIdx.x * 16;
  const int lofs = (l15 * 4 + oct) * 8;

  // stage: sum halves + bias + relu -> hpan (fragment order)
  {
    const int r  = tid >> 4;
    const int c0 = (tid & 15) * 32;
    const float* s0 = S + (size_t)(rb + r) * 512 + c0;
    const float* s1 = s0 + (size_t)B_TOT * 512;
#pragma unroll
    for (int i = 0; i < 8; ++i) {
      const float4_t a = *(const float4_t*)(s0 + i * 4);
      const float4_t b = *(const float4_t*)(s1 + i * 4);
      const float4_t bi = *(const float4_t*)(B1 + c0 + i * 4);
#pragma unroll
      for (int e = 0; e < 4; ++e) {
        const int c  = c0 + i * 4 + e;
        const float hv = fmaxf(a[e] + b[e] + bi[e], 0.0f);
        const int gg = c >> 7, kk = c & 127;
        const int ks = kk >> 5, oc = (kk >> 3) & 3, jj = kk & 7;
        hpan[(gg * 4 + ks) * 512 + (r * 4 + oc) * 8 + jj] = f2b(hv);
      }
    }
  }
  __syncthreads();

  // enc2: wave g, cols g*128 + ni*16 + l15 (ni 0..7), K=128
  float4_t acc[8];
#pragma unroll
  for (int j = 0; j < 8; ++j) acc[j] = (float4_t){0.f, 0.f, 0.f, 0.f};
  {
    const unsigned short* bb = W2p + (size_t)g * 16384 + lofs;
#pragma unroll
    for (int ks = 0; ks < 4; ++ks) {
      const short8_t af = *(const short8_t*)&hpan[(g * 4 + ks) * 512 + lofs];
#pragma unroll
      for (int ni = 0; ni < 8; ++ni) {
        const short8_t bf = *(const short8_t*)(bb + ks * 4096 + ni * 512);
        acc[ni] = __builtin_amdgcn_mfma_f32_16x16x32_bf16(af, bf, acc[ni], 0, 0, 0);
      }
    }
  }

#pragma unroll
  for (int ni = 0; ni < 8; ++ni) {
    const int col = g * 128 + ni * 16 + l15;
    const float b = B2[col];
#pragma unroll
    for (int j = 0; j < 4; ++j)
      mls[(oct * 4 + j) * 516 + col] = acc[ni][j] + b;
  }
  __syncthreads();

  // PoE + reparameterize -> zbp (fragment order)
#pragma unroll
  for (int qq = 0; qq < 4; ++qq) {
    const int idx = qq * 256 + tid;
    const int r   = idx >> 6;
    const int ll  = idx & 63;
    const int m   = kMask[subset_idx[rb + r]];
    float tau = 1.0f, num = 0.0f;
#pragma unroll
    for (int gg = 0; gg < 4; ++gg) {
      if (m & (1 << gg)) {
        const float lv = mls[r * 516 + gg * 128 + 64 + ll];
        const float mu = mls[r * 516 + gg * 128 + ll];
        const float t  = expf(-lv);
        tau += t;
        num = fmaf(t, mu, num);
      }
    }
    const float zv = num / tau + eps[(size_t)(rb + r) * LATD + ll] * rsqrtf(tau);
    zbp[(ll >> 5) * 512 + (r * 4 + ((ll >> 3) & 3)) * 8 + (ll & 7)] = f2b(zv);
  }
  __syncthreads();

  // dec1: wave g -> cols g*64 + ni*16 + l15 (ni 0..3), K=64
  float4_t a3[4];
#pragma unroll
  for (int j = 0; j < 4; ++j) a3[j] = (float4_t){0.f, 0.f, 0.f, 0.f};
  {
    const unsigned short* bb = W3p + (size_t)g * 4096 + lofs;
#pragma unroll
    for (int ks = 0; ks < 2; ++ks) {
      const short8_t af = *(const short8_t*)&zbp[ks * 512 + lofs];
#pragma unroll
      for (int ni = 0; ni < 4; ++ni) {
        const short8_t bf = *(const short8_t*)(bb + ks * 2048 + ni * 512);
        a3[ni] = __builtin_amdgcn_mfma_f32_16x16x32_bf16(af, bf, a3[ni], 0, 0, 0);
      }
    }
  }
#pragma unroll
  for (int ni = 0; ni < 4; ++ni) {
    const int col = g * 64 + ni * 16 + l15;
    const float b = DB1[col];
#pragma unroll
    for (int j = 0; j < 4; ++j)
      Hd[(size_t)(rb + oct * 4 + j) * 256 + col] = f2b(fmaxf(a3[ni][j] + b, 0.0f));
  }
}

// ---------------- dec2: panel-B MFMA + coalesced epilogue (verified) -------
__global__ __launch_bounds__(512) void k_dec2(const unsigned short* __restrict__ Hd,
                                              const unsigned short* __restrict__ W4p,
                                              const float* __restrict__ Bb,
                                              float* __restrict__ Out) {
  __shared__ float obuf[32][264];

  const int tid = threadIdx.x;
  const int w   = tid >> 6;
  const int l   = tid & 63;
  const int g   = w >> 1;
  const int oh  = w & 1;
  const int r0  = blockIdx.x * 32;
  const int ob  = blockIdx.y * 64;
  const int l15 = l & 15;
  const int oct = l >> 4;
  const int lofs = (l15 * 4 + oct) * 8;

  float4_t acc[2][2];
#pragma unroll
  for (int i = 0; i < 2; ++i)
#pragma unroll
    for (int j = 0; j < 2; ++j) acc[i][j] = (float4_t){0.f, 0.f, 0.f, 0.f};

  const unsigned short* bb4 = W4p + ((g * 16 + blockIdx.y) * 2 + oh) * 2048 + lofs;

#pragma unroll
  for (int ks = 0; ks < 2; ++ks) {
    short8_t af[2], bf[2];
#pragma unroll
    for (int mi = 0; mi < 2; ++mi)
      af[mi] = *(const short8_t*)(Hd + (size_t)(r0 + mi * 16 + l15) * 256 +
                                  g * 64 + ks * 32 + oct * 8);
#pragma unroll
    for (int ni = 0; ni < 2; ++ni)
      bf[ni] = *(const short8_t*)(bb4 + ks * 1024 + ni * 512);
#pragma unroll
    for (int mi = 0; mi < 2; ++mi)
#pragma unroll
      for (int ni = 0; ni < 2; ++ni)
        acc[mi][ni] = __builtin_amdgcn_mfma_f32_16x16x32_bf16(af[mi], bf[ni], acc[mi][ni], 0, 0, 0);
  }

#pragma unroll
  for (int ni = 0; ni < 2; ++ni) {
    const int lo = oh * 32 + ni * 16 + l15;
    const float b = Bb[g * 1024 + ob + lo];
#pragma unroll
    for (int mi = 0; mi < 2; ++mi) {
      const int rloc = mi * 16 + oct * 4;
#pragma unroll
      for (int j = 0; j < 4; ++j)
        obuf[rloc + j][4 * lo + g] = acc[mi][ni][j] + b;
    }
  }
  __syncthreads();

#pragma unroll
  for (int i = 0; i < 4; ++i) {
    const int q = tid + i * 512;
    const int row = q >> 6, c4 = q & 63;
    const float4 v = *(const float4*)&obuf[row][c4 * 4];
    *(float4*)(Out + (size_t)(r0 + row) * OBS + 4 * ob + c4 * 4) = v;
  }
}

extern "C" void kernel_launch(void* const* d_in, const int* in_sizes, int n_in,
                              void* d_out, int out_size, void* d_ws, size_t ws_size,
                              hipStream_t stream) {
  const float* X          = (const float*)d_in[0];
  const float* eps        = (const float*)d_in[1];
  const int*   subset_idx = (const int*)  d_in[2];
  const float* enc_w1     = (const float*)d_in[3];
  const float* enc_b1     = (const float*)d_in[4];
  const float* enc_w2     = (const float*)d_in[5];
  const float* enc_b2     = (const float*)d_in[6];
  const float* dec_w1     = (const float*)d_in[7];
  const float* dec_b1     = (const float*)d_in[8];
  const float* dec_w2     = (const float*)d_in[9];
  const float* dec_b2     = (const float*)d_in[10];
  float* out = (float*)d_out;

  char* wsb = (char*)d_ws;
  unsigned short* Xt  = (unsigned short*)wsb;                                 // 64 MB
  float*          S   = (float*)(wsb + (64u << 20));                          // 32 MB (2 halves)
  unsigned short* Hd  = (unsigned short*)(wsb + (96u << 20));                 // 4 MB
  unsigned short* W1p = (unsigned short*)(wsb + (100u << 20));                // 1 MB
  unsigned short* W2p = (unsigned short*)(wsb + (101u << 20));                // 128 KB
  unsigned short* W3p = (unsigned short*)(wsb + (101u << 20) + (128u << 10)); // 32 KB
  unsigned short* W4p = (unsigned short*)(wsb + (101u << 20) + (160u << 10)); // 512 KB

  k_prep<<<3392, 256, 0, stream>>>(enc_w1, enc_w2, dec_w1, dec_w2,
                                   W1p, W2p, W3p, W4p);
  k_prepx<<<4096, 512, 0, stream>>>(X, Xt);
  k_enc1s<<<dim3(256, 8, 2), 256, 0, stream>>>(Xt, W1p, S);
  k_samp2<<<512, 256, 0, stream>>>(S, W2p, W3p, enc_b1, enc_b2, dec_b1,
                                   eps, subset_idx, Hd);
  k_dec2<<<dim3(256, 16), 512, 0, stream>>>(Hd, W4p, dec_b2, out);
}

// Round 12
// 144.877 us; speedup vs baseline: 1.3155x; 1.3155x over previous
//
#include <hip/hip_runtime.h>
#include <hip/hip_bf16.h>
#include <math.h>

#define B_TOT 8192
#define OBS   4096
#define NG    4
#define GSZ   1024
#define LATD  64
#define HDIM  128

typedef __attribute__((ext_vector_type(8))) short   short8_t;
typedef __attribute__((ext_vector_type(8))) unsigned short ushort8_t;
typedef __attribute__((ext_vector_type(4))) float   float4_t;

__constant__ int kMask[15] = {1,2,4,8, 3,5,9,6,10,12, 7,11,13,14, 15};

static __device__ __forceinline__ unsigned short f2b(float x) {
  __hip_bfloat16 b = __float2bfloat16(x);
  return *reinterpret_cast<unsigned short*>(&b);
}
static __device__ __forceinline__ unsigned int pack2(float lo, float hi) {
  return (unsigned int)f2b(lo) | ((unsigned int)f2b(hi) << 16);
}
// async global->LDS, 16B/lane; dest = wave-uniform base (+lane*16), src per-lane
static __device__ __forceinline__ void gl16(const void* g, void* l) {
  __builtin_amdgcn_global_load_lds(
      (const __attribute__((address_space(1))) void*)g,
      (__attribute__((address_space(3))) void*)l, 16, 0, 0);
}

// slot-padded A rows: 4 rows x 256B per 1056B slot (slots stagger banks by 8)
#define SLOT 1056
#define AQ(row) ((((row) >> 2) * SLOT) + (((row) & 3) * 256))

// ------------- weight prep: bf16 + fragment-panel layouts (verified R9) ----
#define N1 524288
#define N2 65536
#define N3 16384
#define N4 262144
__global__ __launch_bounds__(256) void k_prep(const float* __restrict__ w1,
                                              const float* __restrict__ w2,
                                              const float* __restrict__ w3,
                                              const float* __restrict__ w4,
                                              unsigned short* __restrict__ W1p,
                                              unsigned short* __restrict__ W2p,
                                              unsigned short* __restrict__ W3p,
                                              unsigned short* __restrict__ W4p) {
  const int i = blockIdx.x * 256 + threadIdx.x;
  if (i < N1) {
    const int j = i & 7, oct = (i >> 3) & 3, l15 = (i >> 5) & 15;
    const int ni = (i >> 9) & 1, ks = (i >> 10) & 31;
    const int w = (i >> 15) & 3, g = (i >> 17) & 3;
    const int k = ks * 32 + oct * 8 + j;
    const int h = w * 32 + ni * 16 + l15;
    W1p[i] = f2b(w1[g * 131072 + k * 128 + h]);
  } else if (i < N1 + N2) {
    const int idx = i - N1;
    const int j = idx & 7, oct = (idx >> 3) & 3, l15 = (idx >> 5) & 15;
    const int ni = (idx >> 9) & 7, ks = (idx >> 12) & 3, g = (idx >> 14) & 3;
    const int k = ks * 32 + oct * 8 + j;
    const int col = ni * 16 + l15;
    W2p[idx] = f2b(w2[g * 16384 + k * 128 + col]);
  } else if (i < N1 + N2 + N3) {
    const int idx = i - N1 - N2;
    const int j = idx & 7, oct = (idx >> 3) & 3, l15 = (idx >> 5) & 15;
    const int ni = (idx >> 9) & 3, ks = (idx >> 11) & 1, g = (idx >> 12) & 3;
    const int k = ks * 32 + oct * 8 + j;
    const int m = ni * 16 + l15;
    W3p[idx] = f2b(w3[g * 4096 + k * 64 + m]);
  } else if (i < N1 + N2 + N3 + N4) {
    const int idx = i - N1 - N2 - N3;
    const int j = idx & 7, oct = (idx >> 3) & 3, l15 = (idx >> 5) & 15;
    const int ni = (idx >> 9) & 1, ks = (idx >> 10) & 1;
    const int oh = (idx >> 11) & 1, ob = (idx >> 12) & 15, g = (idx >> 16) & 3;
    const int k = ks * 32 + oct * 8 + j;
    const int o = ob * 64 + oh * 32 + ni * 16 + l15;
    W4p[idx] = f2b(w4[g * 65536 + k * 1024 + o]);
  }
}

// ---------------- X de-interleave: Xt[b][g][k] = bf16(X[b][4k+g]) ----------
__global__ __launch_bounds__(512) void k_prepx(const float* __restrict__ X,
                                               unsigned short* __restrict__ Xt) {
  const int t = threadIdx.x;
  const int b = blockIdx.x * 2 + (t >> 8);
  const int t256 = t & 255;
  const float* p = X + (size_t)b * OBS + t256 * 16;
  const float4_t f0 = *(const float4_t*)(p);
  const float4_t f1 = *(const float4_t*)(p + 4);
  const float4_t f2 = *(const float4_t*)(p + 8);
  const float4_t f3 = *(const float4_t*)(p + 12);
  const int k0 = t256 * 4;
  unsigned short* q = Xt + (size_t)b * OBS;
#pragma unroll
  for (int g = 0; g < 4; ++g) {
    uint2 v;
    v.x = pack2(f0[g], f1[g]);
    v.y = pack2(f2[g], f3[g]);
    *(uint2*)(q + g * GSZ + k0) = v;
  }
}

// -------- enc1b: 128-row blocks, B-amortized split-K GEMM ------------------
// grid (64 rb, 4 g, 2 half) = 512 blocks x 512 thr (8 waves: wm=w&3 rowgrp,
// wn=w>>2 colgrp). Per block: 128 rows x 128 cols (one g), K=512 (half),
// 4 chunks of BK=128. A via global_load_lds (per-lane src, slot-padded dest,
// double-buffered, 1 barrier/chunk); B via direct 1KB panel loads (L2-hot,
// re-read only 64x thanks to 128-row tiles). Partial sums -> S[half] fp32.
__global__ __launch_bounds__(512, 2) void k_enc1b(const unsigned short* __restrict__ Xt,
                                                  const unsigned short* __restrict__ W1p,
                                                  float* __restrict__ S) {
  __shared__ __align__(16) char As[2 * 32 * SLOT];   // 67.5 KB

  const int tid = threadIdx.x;
  const int w   = tid >> 6;
  const int l   = tid & 63;
  const int wm  = w & 3;            // row group (32 rows)
  const int wn  = w >> 2;           // col group (64 cols)
  const int l15 = l & 15;
  const int oct = l >> 4;
  const int rb  = blockIdx.x * 128;
  const int g   = blockIdx.y;
  const int z   = blockIdx.z;       // K half
  const int lofs = (l15 * 4 + oct) * 8;   // panel lane offset (shorts)

  // staging source base for this lane: row = slot*4 + (l>>4), 16B chunk (l&15)
  const unsigned short* const xsrc =
      Xt + (size_t)(rb + (l >> 4)) * OBS + g * GSZ + z * 512 + (l & 15) * 8;

  // prologue: stage chunk 0 into buf 0 (each wave: 4 slots)
#pragma unroll
  for (int i = 0; i < 4; ++i) {
    const int s = i * 8 + w;        // slot 0..31 (4 rows each)
    gl16(xsrc + (size_t)(s * 4) * OBS, As + s * SLOT);
  }
  __syncthreads();

  float4_t acc[2][4];
#pragma unroll
  for (int i = 0; i < 2; ++i)
#pragma unroll
    for (int j = 0; j < 4; ++j) acc[i][j] = (float4_t){0.f, 0.f, 0.f, 0.f};

  const unsigned short* const bbase = W1p + (size_t)g * 131072 + (size_t)(wn * 2) * 32768;

  for (int c = 0; c < 4; ++c) {
    const int cur = c & 1;
    if (c < 3) {   // async-prefetch next chunk into alt buffer
#pragma unroll
      for (int i = 0; i < 4; ++i) {
        const int s = i * 8 + w;
        gl16(xsrc + (size_t)(s * 4) * OBS + (c + 1) * 128,
             As + (cur ^ 1) * 32 * SLOT + s * SLOT);
      }
    }
    // compute chunk c: LDS A + direct-global B panels
#pragma unroll
    for (int ks = 0; ks < 4; ++ks) {
      const int ksg = z * 16 + c * 4 + ks;
      short8_t af[2], bf[4];
#pragma unroll
      for (int mi = 0; mi < 2; ++mi)
        af[mi] = *(const short8_t*)(As + cur * 32 * SLOT +
                                    AQ(wm * 32 + mi * 16 + l15) +
                                    ks * 64 + oct * 16);
#pragma unroll
      for (int ni = 0; ni < 4; ++ni)
        bf[ni] = *(const short8_t*)(bbase + (size_t)(ni >> 1) * 32768 +
                                    (size_t)ksg * 1024 + (ni & 1) * 512 + lofs);
#pragma unroll
      for (int mi = 0; mi < 2; ++mi)
#pragma unroll
        for (int ni = 0; ni < 4; ++ni)
          acc[mi][ni] = __builtin_amdgcn_mfma_f32_16x16x32_bf16(af[mi], bf[ni], acc[mi][ni], 0, 0, 0);
    }
    __syncthreads();   // drains prefetch writes + compute reads
  }

  // store partials: S[half][row][col] fp32
  float* const sp = S + (size_t)z * B_TOT * 512;
#pragma unroll
  for (int ni = 0; ni < 4; ++ni) {
    const int col = g * 128 + wn * 64 + ni * 16 + l15;
#pragma unroll
    for (int mi = 0; mi < 2; ++mi) {
      const int row = rb + wm * 32 + mi * 16 + oct * 4;
#pragma unroll
      for (int j = 0; j < 4; ++j)
        sp[(size_t)(row + j) * 512 + col] = acc[mi][ni][j];
    }
  }
}

// -------- samp2: h=relu(S0+S1+b1) -> enc2 -> PoE/sample -> dec1 -> Hd ------
// (verified R11) 512 blocks x 256 thr.
__global__ __launch_bounds__(256, 3) void k_samp2(const float* __restrict__ S,
                                                  const unsigned short* __restrict__ W2p,
                                                  const unsigned short* __restrict__ W3p,
                                                  const float* __restrict__ B1,
                                                  const float* __restrict__ B2,
                                                  const float* __restrict__ DB1,
                                                  const float* __restrict__ eps,
                                                  const int*   __restrict__ subset_idx,
                                                  unsigned short* __restrict__ Hd) {
  __shared__ __align__(16) unsigned short hpan[16 * 512];
  __shared__ __align__(16) float mls[16 * 516];
  __shared__ __align__(16) unsigned short zbp[2 * 512];

  const int tid = threadIdx.x;
  const int g   = tid >> 6;
  const int l   = tid & 63;
  const int l15 = l & 15;
  const int oct = l >> 4;
  const int rb  = blockIdx.x * 16;
  const int lofs = (l15 * 4 + oct) * 8;

  {
    const int r  = tid >> 4;
    const int c0 = (tid & 15) * 32;
    const float* s0 = S + (size_t)(rb + r) * 512 + c0;
    const float* s1 = s0 + (size_t)B_TOT * 512;
#pragma unroll
    for (int i = 0; i < 8; ++i) {
      const float4_t a = *(const float4_t*)(s0 + i * 4);
      const float4_t b = *(const float4_t*)(s1 + i * 4);
      const float4_t bi = *(const float4_t*)(B1 + c0 + i * 4);
#pragma unroll
      for (int e = 0; e < 4; ++e) {
        const int c  = c0 + i * 4 + e;
        const float hv = fmaxf(a[e] + b[e] + bi[e], 0.0f);
        const int gg = c >> 7, kk = c & 127;
        const int ks = kk >> 5, oc = (kk >> 3) & 3, jj = kk & 7;
        hpan[(gg * 4 + ks) * 512 + (r * 4 + oc) * 8 + jj] = f2b(hv);
      }
    }
  }
  __syncthreads();

  float4_t acc[8];
#pragma unroll
  for (int j = 0; j < 8; ++j) acc[j] = (float4_t){0.f, 0.f, 0.f, 0.f};
  {
    const unsigned short* bb = W2p + (size_t)g * 16384 + lofs;
#pragma unroll
    for (int ks = 0; ks < 4; ++ks) {
      const short8_t af = *(const short8_t*)&hpan[(g * 4 + ks) * 512 + lofs];
#pragma unroll
      for (int ni = 0; ni < 8; ++ni) {
        const short8_t bf = *(const short8_t*)(bb + ks * 4096 + ni * 512);
        acc[ni] = __builtin_amdgcn_mfma_f32_16x16x32_bf16(af, bf, acc[ni], 0, 0, 0);
      }
    }
  }

#pragma unroll
  for (int ni = 0; ni < 8; ++ni) {
    const int col = g * 128 + ni * 16 + l15;
    const float b = B2[col];
#pragma unroll
    for (int j = 0; j < 4; ++j)
      mls[(oct * 4 + j) * 516 + col] = acc[ni][j] + b;
  }
  __syncthreads();

#pragma unroll
  for (int qq = 0; qq < 4; ++qq) {
    const int idx = qq * 256 + tid;
    const int r   = idx >> 6;
    const int ll  = idx & 63;
    const int m   = kMask[subset_idx[rb + r]];
    float tau = 1.0f, num = 0.0f;
#pragma unroll
    for (int gg = 0; gg < 4; ++gg) {
      if (m & (1 << gg)) {
        const float lv = mls[r * 516 + gg * 128 + 64 + ll];
        const float mu = mls[r * 516 + gg * 128 + ll];
        const float t  = expf(-lv);
        tau += t;
        num = fmaf(t, mu, num);
      }
    }
    const float zv = num / tau + eps[(size_t)(rb + r) * LATD + ll] * rsqrtf(tau);
    zbp[(ll >> 5) * 512 + (r * 4 + ((ll >> 3) & 3)) * 8 + (ll & 7)] = f2b(zv);
  }
  __syncthreads();

  float4_t a3[4];
#pragma unroll
  for (int j = 0; j < 4; ++j) a3[j] = (float4_t){0.f, 0.f, 0.f, 0.f};
  {
    const unsigned short* bb = W3p + (size_t)g * 4096 + lofs;
#pragma unroll
    for (int ks = 0; ks < 2; ++ks) {
      const short8_t af = *(const short8_t*)&zbp[ks * 512 + lofs];
#pragma unroll
      for (int ni = 0; ni < 4; ++ni) {
        const short8_t bf = *(const short8_t*)(bb + ks * 2048 + ni * 512);
        a3[ni] = __builtin_amdgcn_mfma_f32_16x16x32_bf16(af, bf, a3[ni], 0, 0, 0);
      }
    }
  }
#pragma unroll
  for (int ni = 0; ni < 4; ++ni) {
    const int col = g * 64 + ni * 16 + l15;
    const float b = DB1[col];
#pragma unroll
    for (int j = 0; j < 4; ++j)
      Hd[(size_t)(rb + oct * 4 + j) * 256 + col] = f2b(fmaxf(a3[ni][j] + b, 0.0f));
  }
}

// ---------------- dec2: panel-B MFMA + coalesced epilogue (verified) -------
__global__ __launch_bounds__(512) void k_dec2(const unsigned short* __restrict__ Hd,
                                              const unsigned short* __restrict__ W4p,
                                              const float* __restrict__ Bb,
                                              float* __restrict__ Out) {
  __shared__ float obuf[32][264];

  const int tid = threadIdx.x;
  const int w   = tid >> 6;
  const int l   = tid & 63;
  const int g   = w >> 1;
  const int oh  = w & 1;
  const int r0  = blockIdx.x * 32;
  const int ob  = blockIdx.y * 64;
  const int l15 = l & 15;
  const int oct = l >> 4;
  const int lofs = (l15 * 4 + oct) * 8;

  float4_t acc[2][2];
#pragma unroll
  for (int i = 0; i < 2; ++i)
#pragma unroll
    for (int j = 0; j < 2; ++j) acc[i][j] = (float4_t){0.f, 0.f, 0.f, 0.f};

  const unsigned short* bb4 = W4p + ((g * 16 + blockIdx.y) * 2 + oh) * 2048 + lofs;

#pragma unroll
  for (int ks = 0; ks < 2; ++ks) {
    short8_t af[2], bf[2];
#pragma unroll
    for (int mi = 0; mi < 2; ++mi)
      af[mi] = *(const short8_t*)(Hd + (size_t)(r0 + mi * 16 + l15) * 256 +
                                  g * 64 + ks * 32 + oct * 8);
#pragma unroll
    for (int ni = 0; ni < 2; ++ni)
      bf[ni] = *(const short8_t*)(bb4 + ks * 1024 + ni * 512);
#pragma unroll
    for (int mi = 0; mi < 2; ++mi)
#pragma unroll
      for (int ni = 0; ni < 2; ++ni)
        acc[mi][ni] = __builtin_amdgcn_mfma_f32_16x16x32_bf16(af[mi], bf[ni], acc[mi][ni], 0, 0, 0);
  }

#pragma unroll
  for (int ni = 0; ni < 2; ++ni) {
    const int lo = oh * 32 + ni * 16 + l15;
    const float b = Bb[g * 1024 + ob + lo];
#pragma unroll
    for (int mi = 0; mi < 2; ++mi) {
      const int rloc = mi * 16 + oct * 4;
#pragma unroll
      for (int j = 0; j < 4; ++j)
        obuf[rloc + j][4 * lo + g] = acc[mi][ni][j] + b;
    }
  }
  __syncthreads();

#pragma unroll
  for (int i = 0; i < 4; ++i) {
    const int q = tid + i * 512;
    const int row = q >> 6, c4 = q & 63;
    const float4 v = *(const float4*)&obuf[row][c4 * 4];
    *(float4*)(Out + (size_t)(r0 + row) * OBS + 4 * ob + c4 * 4) = v;
  }
}

extern "C" void kernel_launch(void* const* d_in, const int* in_sizes, int n_in,
                              void* d_out, int out_size, void* d_ws, size_t ws_size,
                              hipStream_t stream) {
  const float* X          = (const float*)d_in[0];
  const float* eps        = (const float*)d_in[1];
  const int*   subset_idx = (const int*)  d_in[2];
  const float* enc_w1     = (const float*)d_in[3];
  const float* enc_b1     = (const float*)d_in[4];
  const float* enc_w2     = (const float*)d_in[5];
  const float* enc_b2     = (const float*)d_in[6];
  const float* dec_w1     = (const float*)d_in[7];
  const float* dec_b1     = (const float*)d_in[8];
  const float* dec_w2     = (const float*)d_in[9];
  const float* dec_b2     = (const float*)d_in[10];
  float* out = (float*)d_out;

  char* wsb = (char*)d_ws;
  unsigned short* Xt  = (unsigned short*)wsb;                                 // 64 MB
  float*          S   = (float*)(wsb + (64u << 20));                          // 32 MB
  unsigned short* Hd  = (unsigned short*)(wsb + (96u << 20));                 // 4 MB
  unsigned short* W1p = (unsigned short*)(wsb + (100u << 20));                // 1 MB
  unsigned short* W2p = (unsigned short*)(wsb + (101u << 20));                // 128 KB
  unsigned short* W3p = (unsigned short*)(wsb + (101u << 20) + (128u << 10)); // 32 KB
  unsigned short* W4p = (unsigned short*)(wsb + (101u << 20) + (160u << 10)); // 512 KB

  k_prep<<<3392, 256, 0, stream>>>(enc_w1, enc_w2, dec_w1, dec_w2,
                                   W1p, W2p, W3p, W4p);
  k_prepx<<<4096, 512, 0, stream>>>(X, Xt);
  k_enc1b<<<dim3(64, 4, 2), 512, 0, stream>>>(Xt, W1p, S);
  k_samp2<<<512, 256, 0, stream>>>(S, W2p, W3p, enc_b1, enc_b2, dec_b1,
                                   eps, subset_idx, Hd);
  k_dec2<<<dim3(256, 16), 512, 0, stream>>>(Hd, W4p, dec_b2, out);
}

// Round 13
// 143.662 us; speedup vs baseline: 1.3267x; 1.0085x over previous
//
#include <hip/hip_runtime.h>
#include <hip/hip_bf16.h>
#include <math.h>

#define B_TOT 8192
#define OBS   4096
#define NG    4
#define GSZ   1024
#define LATD  64
#define HDIM  128

typedef __attribute__((ext_vector_type(8))) short   short8_t;
typedef __attribute__((ext_vector_type(8))) unsigned short ushort8_t;
typedef __attribute__((ext_vector_type(4))) float   float4_t;

__constant__ int kMask[15] = {1,2,4,8, 3,5,9,6,10,12, 7,11,13,14, 15};

static __device__ __forceinline__ unsigned short f2b(float x) {
  __hip_bfloat16 b = __float2bfloat16(x);
  return *reinterpret_cast<unsigned short*>(&b);
}
static __device__ __forceinline__ unsigned int pack2(float lo, float hi) {
  return (unsigned int)f2b(lo) | ((unsigned int)f2b(hi) << 16);
}
// async global->LDS, 16B/lane; dest = wave-uniform base (+lane*16), src per-lane
static __device__ __forceinline__ void gl16(const void* g, void* l) {
  __builtin_amdgcn_global_load_lds(
      (const __attribute__((address_space(1))) void*)g,
      (__attribute__((address_space(3))) void*)l, 16, 0, 0);
}

// slot-padded A rows: 4 rows x 256B per 1056B slot
#define SLOT 1056
#define AQ(row) ((((row) >> 2) * SLOT) + (((row) & 3) * 256))

// ------------- weight prep: bf16 + fragment-panel layouts (verified R9) ----
#define N1 524288
#define N2 65536
#define N3 16384
#define N4 262144
__global__ __launch_bounds__(256) void k_prep(const float* __restrict__ w1,
                                              const float* __restrict__ w2,
                                              const float* __restrict__ w3,
                                              const float* __restrict__ w4,
                                              unsigned short* __restrict__ W1p,
                                              unsigned short* __restrict__ W2p,
                                              unsigned short* __restrict__ W3p,
                                              unsigned short* __restrict__ W4p) {
  const int i = blockIdx.x * 256 + threadIdx.x;
  if (i < N1) {
    const int j = i & 7, oct = (i >> 3) & 3, l15 = (i >> 5) & 15;
    const int ni = (i >> 9) & 1, ks = (i >> 10) & 31;
    const int w = (i >> 15) & 3, g = (i >> 17) & 3;
    const int k = ks * 32 + oct * 8 + j;
    const int h = w * 32 + ni * 16 + l15;
    W1p[i] = f2b(w1[g * 131072 + k * 128 + h]);
  } else if (i < N1 + N2) {
    const int idx = i - N1;
    const int j = idx & 7, oct = (idx >> 3) & 3, l15 = (idx >> 5) & 15;
    const int ni = (idx >> 9) & 7, ks = (idx >> 12) & 3, g = (idx >> 14) & 3;
    const int k = ks * 32 + oct * 8 + j;
    const int col = ni * 16 + l15;
    W2p[idx] = f2b(w2[g * 16384 + k * 128 + col]);
  } else if (i < N1 + N2 + N3) {
    const int idx = i - N1 - N2;
    const int j = idx & 7, oct = (idx >> 3) & 3, l15 = (idx >> 5) & 15;
    const int ni = (idx >> 9) & 3, ks = (idx >> 11) & 1, g = (idx >> 12) & 3;
    const int k = ks * 32 + oct * 8 + j;
    const int m = ni * 16 + l15;
    W3p[idx] = f2b(w3[g * 4096 + k * 64 + m]);
  } else if (i < N1 + N2 + N3 + N4) {
    const int idx = i - N1 - N2 - N3;
    const int j = idx & 7, oct = (idx >> 3) & 3, l15 = (idx >> 5) & 15;
    const int ni = (idx >> 9) & 1, ks = (idx >> 10) & 1;
    const int oh = (idx >> 11) & 1, ob = (idx >> 12) & 15, g = (idx >> 16) & 3;
    const int k = ks * 32 + oct * 8 + j;
    const int o = ob * 64 + oh * 32 + ni * 16 + l15;
    W4p[idx] = f2b(w4[g * 65536 + k * 1024 + o]);
  }
}

// ---------------- X de-interleave: Xt[b][g][k] = bf16(X[b][4k+g]) ----------
__global__ __launch_bounds__(512) void k_prepx(const float* __restrict__ X,
                                               unsigned short* __restrict__ Xt) {
  const int t = threadIdx.x;
  const int b = blockIdx.x * 2 + (t >> 8);
  const int t256 = t & 255;
  const float* p = X + (size_t)b * OBS + t256 * 16;
  const float4_t f0 = *(const float4_t*)(p);
  const float4_t f1 = *(const float4_t*)(p + 4);
  const float4_t f2 = *(const float4_t*)(p + 8);
  const float4_t f3 = *(const float4_t*)(p + 12);
  const int k0 = t256 * 4;
  unsigned short* q = Xt + (size_t)b * OBS;
#pragma unroll
  for (int g = 0; g < 4; ++g) {
    uint2 v;
    v.x = pack2(f0[g], f1[g]);
    v.y = pack2(f2[g], f3[g]);
    *(uint2*)(q + g * GSZ + k0) = v;
  }
}

// -------- enc1b: 128-row blocks, B-amortized split-K GEMM (verified R12) ---
__global__ __launch_bounds__(512, 2) void k_enc1b(const unsigned short* __restrict__ Xt,
                                                  const unsigned short* __restrict__ W1p,
                                                  float* __restrict__ S) {
  __shared__ __align__(16) char As[2 * 32 * SLOT];

  const int tid = threadIdx.x;
  const int w   = tid >> 6;
  const int l   = tid & 63;
  const int wm  = w & 3;
  const int wn  = w >> 2;
  const int l15 = l & 15;
  const int oct = l >> 4;
  const int rb  = blockIdx.x * 128;
  const int g   = blockIdx.y;
  const int z   = blockIdx.z;
  const int lofs = (l15 * 4 + oct) * 8;

  const unsigned short* const xsrc =
      Xt + (size_t)(rb + (l >> 4)) * OBS + g * GSZ + z * 512 + (l & 15) * 8;

#pragma unroll
  for (int i = 0; i < 4; ++i) {
    const int s = i * 8 + w;
    gl16(xsrc + (size_t)(s * 4) * OBS, As + s * SLOT);
  }
  __syncthreads();

  float4_t acc[2][4];
#pragma unroll
  for (int i = 0; i < 2; ++i)
#pragma unroll
    for (int j = 0; j < 4; ++j) acc[i][j] = (float4_t){0.f, 0.f, 0.f, 0.f};

  const unsigned short* const bbase = W1p + (size_t)g * 131072 + (size_t)(wn * 2) * 32768;

  for (int c = 0; c < 4; ++c) {
    const int cur = c & 1;
    if (c < 3) {
#pragma unroll
      for (int i = 0; i < 4; ++i) {
        const int s = i * 8 + w;
        gl16(xsrc + (size_t)(s * 4) * OBS + (c + 1) * 128,
             As + (cur ^ 1) * 32 * SLOT + s * SLOT);
      }
    }
#pragma unroll
    for (int ks = 0; ks < 4; ++ks) {
      const int ksg = z * 16 + c * 4 + ks;
      short8_t af[2], bf[4];
#pragma unroll
      for (int mi = 0; mi < 2; ++mi)
        af[mi] = *(const short8_t*)(As + cur * 32 * SLOT +
                                    AQ(wm * 32 + mi * 16 + l15) +
                                    ks * 64 + oct * 16);
#pragma unroll
      for (int ni = 0; ni < 4; ++ni)
        bf[ni] = *(const short8_t*)(bbase + (size_t)(ni >> 1) * 32768 +
                                    (size_t)ksg * 1024 + (ni & 1) * 512 + lofs);
#pragma unroll
      for (int mi = 0; mi < 2; ++mi)
#pragma unroll
        for (int ni = 0; ni < 4; ++ni)
          acc[mi][ni] = __builtin_amdgcn_mfma_f32_16x16x32_bf16(af[mi], bf[ni], acc[mi][ni], 0, 0, 0);
    }
    __syncthreads();
  }

  float* const sp = S + (size_t)z * B_TOT * 512;
#pragma unroll
  for (int ni = 0; ni < 4; ++ni) {
    const int col = g * 128 + wn * 64 + ni * 16 + l15;
#pragma unroll
    for (int mi = 0; mi < 2; ++mi) {
      const int row = rb + wm * 32 + mi * 16 + oct * 4;
#pragma unroll
      for (int j = 0; j < 4; ++j)
        sp[(size_t)(row + j) * 512 + col] = acc[mi][ni][j];
    }
  }
}

// -------- samp3: h=relu(S0+S1+b1) [row-major LDS] -> enc2 -> PoE -> dec1 ---
// 512 blocks x 256 thr (4 waves; wave = group). Block = 16 batch rows.
// vs samp2: h staged ROW-MAJOR bf16 via vector writes (no scalar scatter);
// enc2 A-frag = one ds_read_b128. PoE/zbp/dec1 identical to verified samp2.
__global__ __launch_bounds__(256, 3) void k_samp3(const float* __restrict__ S,
                                                  const unsigned short* __restrict__ W2p,
                                                  const unsigned short* __restrict__ W3p,
                                                  const float* __restrict__ B1,
                                                  const float* __restrict__ B2,
                                                  const float* __restrict__ DB1,
                                                  const float* __restrict__ eps,
                                                  const int*   __restrict__ subset_idx,
                                                  unsigned short* __restrict__ Hd) {
  __shared__ __align__(16) unsigned short hrow[16][520];   // 16.6 KB row-major
  __shared__ __align__(16) float mls[16 * 516];            // 33 KB
  __shared__ __align__(16) unsigned short zbp[2 * 512];    // 2 KB

  const int tid = threadIdx.x;
  const int g   = tid >> 6;
  const int l   = tid & 63;
  const int l15 = l & 15;
  const int oct = l >> 4;
  const int rb  = blockIdx.x * 16;
  const int lofs = (l15 * 4 + oct) * 8;

  // stage: h = relu(S0+S1+b1) -> hrow (coalesced reads, vector LDS writes)
  {
    const int r  = tid >> 4;
    const int c0 = (tid & 15) * 32;
    const float* s0 = S + (size_t)(rb + r) * 512 + c0;
    const float* s1 = s0 + (size_t)B_TOT * 512;
    unsigned int hv[8];
#pragma unroll
    for (int i = 0; i < 8; ++i) {
      const float4_t a  = *(const float4_t*)(s0 + i * 4);
      const float4_t b  = *(const float4_t*)(s1 + i * 4);
      const float4_t bi = *(const float4_t*)(B1 + c0 + i * 4);
      hv[i] = pack2(fmaxf(a[0] + b[0] + bi[0], 0.0f),
                    fmaxf(a[1] + b[1] + bi[1], 0.0f));
      hv[i] |= 0;  // keep simple; second pair packed below
      const unsigned int hi2 = pack2(fmaxf(a[2] + b[2] + bi[2], 0.0f),
                                     fmaxf(a[3] + b[3] + bi[3], 0.0f));
      *(uint2*)&hrow[r][c0 + i * 4] = (uint2){hv[i], hi2};
    }
  }
  __syncthreads();

  // enc2: wave g, cols g*128 + ni*16 + l15 (ni 0..7), K=128; A = ds_read_b128
  float4_t acc[8];
#pragma unroll
  for (int j = 0; j < 8; ++j) acc[j] = (float4_t){0.f, 0.f, 0.f, 0.f};
  {
    const unsigned short* bb = W2p + (size_t)g * 16384 + lofs;
#pragma unroll
    for (int ks = 0; ks < 4; ++ks) {
      const short8_t af = *(const short8_t*)&hrow[l15][g * 128 + ks * 32 + oct * 8];
#pragma unroll
      for (int ni = 0; ni < 8; ++ni) {
        const short8_t bf = *(const short8_t*)(bb + ks * 4096 + ni * 512);
        acc[ni] = __builtin_amdgcn_mfma_f32_16x16x32_bf16(af, bf, acc[ni], 0, 0, 0);
      }
    }
  }

  // mls (separate array -> no barrier needed before writes)
#pragma unroll
  for (int ni = 0; ni < 8; ++ni) {
    const int col = g * 128 + ni * 16 + l15;
    const float b = B2[col];
#pragma unroll
    for (int j = 0; j < 4; ++j)
      mls[(oct * 4 + j) * 516 + col] = acc[ni][j] + b;
  }
  __syncthreads();

  // PoE + reparameterize -> zbp (fragment order; verified samp2 code)
#pragma unroll
  for (int qq = 0; qq < 4; ++qq) {
    const int idx = qq * 256 + tid;
    const int r   = idx >> 6;
    const int ll  = idx & 63;
    const int m   = kMask[subset_idx[rb + r]];
    float tau = 1.0f, num = 0.0f;
#pragma unroll
    for (int gg = 0; gg < 4; ++gg) {
      if (m & (1 << gg)) {
        const float lv = mls[r * 516 + gg * 128 + 64 + ll];
        const float mu = mls[r * 516 + gg * 128 + ll];
        const float t  = expf(-lv);
        tau += t;
        num = fmaf(t, mu, num);
      }
    }
    const float zv = num / tau + eps[(size_t)(rb + r) * LATD + ll] * rsqrtf(tau);
    zbp[(ll >> 5) * 512 + (r * 4 + ((ll >> 3) & 3)) * 8 + (ll & 7)] = f2b(zv);
  }
  __syncthreads();

  // dec1: wave g -> cols g*64 + ni*16 + l15 (ni 0..3), K=64 (verified)
  float4_t a3[4];
#pragma unroll
  for (int j = 0; j < 4; ++j) a3[j] = (float4_t){0.f, 0.f, 0.f, 0.f};
  {
    const unsigned short* bb = W3p + (size_t)g * 4096 + lofs;
#pragma unroll
    for (int ks = 0; ks < 2; ++ks) {
      const short8_t af = *(const short8_t*)&zbp[ks * 512 + lofs];
#pragma unroll
      for (int ni = 0; ni < 4; ++ni) {
        const short8_t bf = *(const short8_t*)(bb + ks * 2048 + ni * 512);
        a3[ni] = __builtin_amdgcn_mfma_f32_16x16x32_bf16(af, bf, a3[ni], 0, 0, 0);
      }
    }
  }
#pragma unroll
  for (int ni = 0; ni < 4; ++ni) {
    const int col = g * 64 + ni * 16 + l15;
    const float b = DB1[col];
#pragma unroll
    for (int j = 0; j < 4; ++j)
      Hd[(size_t)(rb + oct * 4 + j) * 256 + col] = f2b(fmaxf(a3[ni][j] + b, 0.0f));
  }
}

// ---------------- dec2: panel-B MFMA + coalesced epilogue (verified) -------
__global__ __launch_bounds__(512) void k_dec2(const unsigned short* __restrict__ Hd,
                                              const unsigned short* __restrict__ W4p,
                                              const float* __restrict__ Bb,
                                              float* __restrict__ Out) {
  __shared__ float obuf[32][264];

  const int tid = threadIdx.x;
  const int w   = tid >> 6;
  const int l   = tid & 63;
  const int g   = w >> 1;
  const int oh  = w & 1;
  const int r0  = blockIdx.x * 32;
  const int ob  = blockIdx.y * 64;
  const int l15 = l & 15;
  const int oct = l >> 4;
  const int lofs = (l15 * 4 + oct) * 8;

  float4_t acc[2][2];
#pragma unroll
  for (int i = 0; i < 2; ++i)
#pragma unroll
    for (int j = 0; j < 2; ++j) acc[i][j] = (float4_t){0.f, 0.f, 0.f, 0.f};

  const unsigned short* bb4 = W4p + ((g * 16 + blockIdx.y) * 2 + oh) * 2048 + lofs;

#pragma unroll
  for (int ks = 0; ks < 2; ++ks) {
    short8_t af[2], bf[2];
#pragma unroll
    for (int mi = 0; mi < 2; ++mi)
      af[mi] = *(const short8_t*)(Hd + (size_t)(r0 + mi * 16 + l15) * 256 +
                                  g * 64 + ks * 32 + oct * 8);
#pragma unroll
    for (int ni = 0; ni < 2; ++ni)
      bf[ni] = *(const short8_t*)(bb4 + ks * 1024 + ni * 512);
#pragma unroll
    for (int mi = 0; mi < 2; ++mi)
#pragma unroll
      for (int ni = 0; ni < 2; ++ni)
        acc[mi][ni] = __builtin_amdgcn_mfma_f32_16x16x32_bf16(af[mi], bf[ni], acc[mi][ni], 0, 0, 0);
  }

#pragma unroll
  for (int ni = 0; ni < 2; ++ni) {
    const int lo = oh * 32 + ni * 16 + l15;
    const float b = Bb[g * 1024 + ob + lo];
#pragma unroll
    for (int mi = 0; mi < 2; ++mi) {
      const int rloc = mi * 16 + oct * 4;
#pragma unroll
      for (int j = 0; j < 4; ++j)
        obuf[rloc + j][4 * lo + g] = acc[mi][ni][j] + b;
    }
  }
  __syncthreads();

#pragma unroll
  for (int i = 0; i < 4; ++i) {
    const int q = tid + i * 512;
    const int row = q >> 6, c4 = q & 63;
    const float4 v = *(const float4*)&obuf[row][c4 * 4];
    *(float4*)(Out + (size_t)(r0 + row) * OBS + 4 * ob + c4 * 4) = v;
  }
}

extern "C" void kernel_launch(void* const* d_in, const int* in_sizes, int n_in,
                              void* d_out, int out_size, void* d_ws, size_t ws_size,
                              hipStream_t stream) {
  const float* X          = (const float*)d_in[0];
  const float* eps        = (const float*)d_in[1];
  const int*   subset_idx = (const int*)  d_in[2];
  const float* enc_w1     = (const float*)d_in[3];
  const float* enc_b1     = (const float*)d_in[4];
  const float* enc_w2     = (const float*)d_in[5];
  const float* enc_b2     = (const float*)d_in[6];
  const float* dec_w1     = (const float*)d_in[7];
  const float* dec_b1     = (const float*)d_in[8];
  const float* dec_w2     = (const float*)d_in[9];
  const float* dec_b2     = (const float*)d_in[10];
  float* out = (float*)d_out;

  char* wsb = (char*)d_ws;
  unsigned short* Xt  = (unsigned short*)wsb;                                 // 64 MB
  float*          S   = (float*)(wsb + (64u << 20));                          // 32 MB
  unsigned short* Hd  = (unsigned short*)(wsb + (96u << 20));                 // 4 MB
  unsigned short* W1p = (unsigned short*)(wsb + (100u << 20));                // 1 MB
  unsigned short* W2p = (unsigned short*)(wsb + (101u << 20));                // 128 KB
  unsigned short* W3p = (unsigned short*)(wsb + (101u << 20) + (128u << 10)); // 32 KB
  unsigned short* W4p = (unsigned short*)(wsb + (101u << 20) + (160u << 10)); // 512 KB

  k_prep<<<3392, 256, 0, stream>>>(enc_w1, enc_w2, dec_w1, dec_w2,
                                   W1p, W2p, W3p, W4p);
  k_prepx<<<4096, 512, 0, stream>>>(X, Xt);
  k_enc1b<<<dim3(64, 4, 2), 512, 0, stream>>>(Xt, W1p, S);
  k_samp3<<<512, 256, 0, stream>>>(S, W2p, W3p, enc_b1, enc_b2, dec_b1,
                                   eps, subset_idx, Hd);
  k_dec2<<<dim3(256, 16), 512, 0, stream>>>(Hd, W4p, dec_b2, out);
}

// Round 14
// 129.203 us; speedup vs baseline: 1.4751x; 1.1119x over previous
//
#include <hip/hip_runtime.h>
#include <hip/hip_bf16.h>
#include <math.h>

#define B_TOT 8192
#define OBS   4096
#define NG    4
#define GSZ   1024
#define LATD  64
#define HDIM  128

typedef __attribute__((ext_vector_type(8))) short   short8_t;
typedef __attribute__((ext_vector_type(8))) unsigned short ushort8_t;
typedef __attribute__((ext_vector_type(4))) float   float4_t;

__constant__ int kMask[15] = {1,2,4,8, 3,5,9,6,10,12, 7,11,13,14, 15};

static __device__ __forceinline__ unsigned short f2b(float x) {
  __hip_bfloat16 b = __float2bfloat16(x);
  return *reinterpret_cast<unsigned short*>(&b);
}
static __device__ __forceinline__ unsigned int pack2(float lo, float hi) {
  return (unsigned int)f2b(lo) | ((unsigned int)f2b(hi) << 16);
}
// async global->LDS, 16B/lane; dest = wave-uniform base (+lane*16), src per-lane
static __device__ __forceinline__ void gl16(const void* g, void* l) {
  __builtin_amdgcn_global_load_lds(
      (const __attribute__((address_space(1))) void*)g,
      (__attribute__((address_space(3))) void*)l, 16, 0, 0);
}

// slot-padded A rows: 4 rows x 256B per 1056B slot
#define SLOT 1056
#define AQ(row) ((((row) >> 2) * SLOT) + (((row) & 3) * 256))

// ------- fused prep: weight panels (verified R9 bodies) + X de-interleave --
// blocks [0,1696): weights, i = bx*512+tid covers exactly N1+N2+N3+N4.
// blocks [1696, 1696+4096): Xt[b][g][k] = bf16(X[b][4k+g]).
#define N1 524288
#define N2 65536
#define N3 16384
#define N4 262144
__global__ __launch_bounds__(512) void k_prep0(const float* __restrict__ w1,
                                               const float* __restrict__ w2,
                                               const float* __restrict__ w3,
                                               const float* __restrict__ w4,
                                               const float* __restrict__ X,
                                               unsigned short* __restrict__ W1p,
                                               unsigned short* __restrict__ W2p,
                                               unsigned short* __restrict__ W3p,
                                               unsigned short* __restrict__ W4p,
                                               unsigned short* __restrict__ Xt) {
  const int bx = blockIdx.x;
  if (bx >= 1696) {
    const int t = threadIdx.x;
    const int b = (bx - 1696) * 2 + (t >> 8);
    const int t256 = t & 255;
    const float* p = X + (size_t)b * OBS + t256 * 16;
    const float4_t f0 = *(const float4_t*)(p);
    const float4_t f1 = *(const float4_t*)(p + 4);
    const float4_t f2 = *(const float4_t*)(p + 8);
    const float4_t f3 = *(const float4_t*)(p + 12);
    const int k0 = t256 * 4;
    unsigned short* q = Xt + (size_t)b * OBS;
#pragma unroll
    for (int g = 0; g < 4; ++g) {
      uint2 v;
      v.x = pack2(f0[g], f1[g]);
      v.y = pack2(f2[g], f3[g]);
      *(uint2*)(q + g * GSZ + k0) = v;
    }
    return;
  }
  const int i = bx * 512 + threadIdx.x;
  if (i < N1) {
    const int j = i & 7, oct = (i >> 3) & 3, l15 = (i >> 5) & 15;
    const int ni = (i >> 9) & 1, ks = (i >> 10) & 31;
    const int w = (i >> 15) & 3, g = (i >> 17) & 3;
    const int k = ks * 32 + oct * 8 + j;
    const int h = w * 32 + ni * 16 + l15;
    W1p[i] = f2b(w1[g * 131072 + k * 128 + h]);
  } else if (i < N1 + N2) {
    const int idx = i - N1;
    const int j = idx & 7, oct = (idx >> 3) & 3, l15 = (idx >> 5) & 15;
    const int ni = (idx >> 9) & 7, ks = (idx >> 12) & 3, g = (idx >> 14) & 3;
    const int k = ks * 32 + oct * 8 + j;
    const int col = ni * 16 + l15;
    W2p[idx] = f2b(w2[g * 16384 + k * 128 + col]);
  } else if (i < N1 + N2 + N3) {
    const int idx = i - N1 - N2;
    const int j = idx & 7, oct = (idx >> 3) & 3, l15 = (idx >> 5) & 15;
    const int ni = (idx >> 9) & 3, ks = (idx >> 11) & 1, g = (idx >> 12) & 3;
    const int k = ks * 32 + oct * 8 + j;
    const int m = ni * 16 + l15;
    W3p[idx] = f2b(w3[g * 4096 + k * 64 + m]);
  } else {
    const int idx = i - N1 - N2 - N3;
    const int j = idx & 7, oct = (idx >> 3) & 3, l15 = (idx >> 5) & 15;
    const int ni = (idx >> 9) & 1, ks = (idx >> 10) & 1;
    const int oh = (idx >> 11) & 1, ob = (idx >> 12) & 15, g = (idx >> 16) & 3;
    const int k = ks * 32 + oct * 8 + j;
    const int o = ob * 64 + oh * 32 + ni * 16 + l15;
    W4p[idx] = f2b(w4[g * 65536 + k * 1024 + o]);
  }
}

// -------- enc1c: 128-row x 64-col blocks, FULL K=1024, Hrow bf16 out -------
// grid (64 rb, 4 g, 2 colhalf) = 512 blocks x 512 thr (8 waves: wm=w&3 row-
// grp, wn=w>>2 colgrp-of-32). Same staging/B-panel machinery as verified
// enc1b; 8 chunks of BK=128; epilogue: bias+relu -> LDS repack -> coalesced
// Hrow stores. No S round-trip.
__global__ __launch_bounds__(512, 2) void k_enc1c(const unsigned short* __restrict__ Xt,
                                                  const unsigned short* __restrict__ W1p,
                                                  const float* __restrict__ B1,
                                                  unsigned short* __restrict__ Hrow) {
  __shared__ __align__(16) char As[2 * 32 * SLOT];   // 67.5 KB -> 2 blocks/CU

  const int tid = threadIdx.x;
  const int w   = tid >> 6;
  const int l   = tid & 63;
  const int wm  = w & 3;            // row group (32 rows)
  const int wn  = w >> 2;           // col group (32 cols) within the 64-col half
  const int l15 = l & 15;
  const int oct = l >> 4;
  const int rb  = blockIdx.x * 128;
  const int g   = blockIdx.y;
  const int z   = blockIdx.z;       // column half (64 cols)
  const int lofs = (l15 * 4 + oct) * 8;

  const unsigned short* const xsrc =
      Xt + (size_t)(rb + (l >> 4)) * OBS + g * GSZ + (l & 15) * 8;

  // prologue: stage chunk 0 into buf 0
#pragma unroll
  for (int i = 0; i < 4; ++i) {
    const int s = i * 8 + w;
    gl16(xsrc + (size_t)(s * 4) * OBS, As + s * SLOT);
  }
  __syncthreads();

  float4_t acc[2][2];
#pragma unroll
  for (int i = 0; i < 2; ++i)
#pragma unroll
    for (int j = 0; j < 2; ++j) acc[i][j] = (float4_t){0.f, 0.f, 0.f, 0.f};

  const int cw = z * 2 + wn;        // colgroup 0..3 (matches prep's w field)
  const unsigned short* const bbase = W1p + (size_t)(g * 4 + cw) * 32768 + lofs;

  for (int c = 0; c < 8; ++c) {
    const int cur = c & 1;
    if (c < 7) {   // async-prefetch next chunk into alt buffer
#pragma unroll
      for (int i = 0; i < 4; ++i) {
        const int s = i * 8 + w;
        gl16(xsrc + (size_t)(s * 4) * OBS + (c + 1) * 128,
             As + (cur ^ 1) * 32 * SLOT + s * SLOT);
      }
    }
#pragma unroll
    for (int ks = 0; ks < 4; ++ks) {
      const int ksg = c * 4 + ks;
      short8_t af[2], bf[2];
#pragma unroll
      for (int mi = 0; mi < 2; ++mi)
        af[mi] = *(const short8_t*)(As + cur * 32 * SLOT +
                                    AQ(wm * 32 + mi * 16 + l15) +
                                    ks * 64 + oct * 16);
#pragma unroll
      for (int ni = 0; ni < 2; ++ni)
        bf[ni] = *(const short8_t*)(bbase + (size_t)ksg * 1024 + ni * 512);
#pragma unroll
      for (int mi = 0; mi < 2; ++mi)
#pragma unroll
        for (int ni = 0; ni < 2; ++ni)
          acc[mi][ni] = __builtin_amdgcn_mfma_f32_16x16x32_bf16(af[mi], bf[ni], acc[mi][ni], 0, 0, 0);
    }
    __syncthreads();
  }

  // epilogue: h = relu(acc+b1) -> ob (overlays As buf0; last chunk used buf1)
  unsigned short* const ob = (unsigned short*)As;   // [128][72]
#pragma unroll
  for (int ni = 0; ni < 2; ++ni) {
    const int c32  = ni * 16 + l15;                  // 0..31 within colgroup
    const int gcol = g * 128 + z * 64 + wn * 32 + c32;
    const float b  = B1[gcol];
#pragma unroll
    for (int mi = 0; mi < 2; ++mi)
#pragma unroll
      for (int j = 0; j < 4; ++j)
        ob[(wm * 32 + mi * 16 + oct * 4 + j) * 72 + wn * 32 + c32] =
            f2b(fmaxf(acc[mi][ni][j] + b, 0.0f));
  }
  __syncthreads();

  // coalesced out: thread t -> row t>>2 (0..127), 16-col segment t&3
  {
    const int row = tid >> 2, seg = tid & 3;
    unsigned short* dst = Hrow + (size_t)(rb + row) * 512 + g * 128 + z * 64 + seg * 16;
    const unsigned short* src = &ob[row * 72 + seg * 16];
    *(ushort8_t*)(dst)     = *(const ushort8_t*)(src);
    *(ushort8_t*)(dst + 8) = *(const ushort8_t*)(src + 8);
  }
}

// -------- samp4: enc2 (A direct from Hrow) -> PoE/sample -> dec1 -> Hd -----
// 512 blocks x 256 thr (4 waves; wave = group). Block = 16 batch rows.
// No stage phase: enc2 A-fragments are 16B/lane global loads (dec2 pattern).
__global__ __launch_bounds__(256, 4) void k_samp4(const unsigned short* __restrict__ Hrow,
                                                  const unsigned short* __restrict__ W2p,
                                                  const unsigned short* __restrict__ W3p,
                                                  const float* __restrict__ B2,
                                                  const float* __restrict__ DB1,
                                                  const float* __restrict__ eps,
                                                  const int*   __restrict__ subset_idx,
                                                  unsigned short* __restrict__ Hd) {
  __shared__ __align__(16) float mls[16 * 516];            // 33 KB
  __shared__ __align__(16) unsigned short zbp[2 * 512];    // 2 KB

  const int tid = threadIdx.x;
  const int g   = tid >> 6;
  const int l   = tid & 63;
  const int l15 = l & 15;
  const int oct = l >> 4;
  const int rb  = blockIdx.x * 16;
  const int lofs = (l15 * 4 + oct) * 8;

  // enc2: wave g, cols g*128 + ni*16 + l15 (ni 0..7), K=128
  float4_t acc[8];
#pragma unroll
  for (int j = 0; j < 8; ++j) acc[j] = (float4_t){0.f, 0.f, 0.f, 0.f};
  {
    const unsigned short* arow = Hrow + (size_t)(rb + l15) * 512 + g * 128 + oct * 8;
    const unsigned short* bb   = W2p + (size_t)g * 16384 + lofs;
#pragma unroll
    for (int ks = 0; ks < 4; ++ks) {
      const short8_t af = *(const short8_t*)(arow + ks * 32);
#pragma unroll
      for (int ni = 0; ni < 8; ++ni) {
        const short8_t bf = *(const short8_t*)(bb + ks * 4096 + ni * 512);
        acc[ni] = __builtin_amdgcn_mfma_f32_16x16x32_bf16(af, bf, acc[ni], 0, 0, 0);
      }
    }
  }

#pragma unroll
  for (int ni = 0; ni < 8; ++ni) {
    const int col = g * 128 + ni * 16 + l15;
    const float b = B2[col];
#pragma unroll
    for (int j = 0; j < 4; ++j)
      mls[(oct * 4 + j) * 516 + col] = acc[ni][j] + b;
  }
  __syncthreads();

  // PoE + reparameterize -> zbp (fragment order; verified)
#pragma unroll
  for (int qq = 0; qq < 4; ++qq) {
    const int idx = qq * 256 + tid;
    const int r   = idx >> 6;
    const int ll  = idx & 63;
    const int m   = kMask[subset_idx[rb + r]];
    float tau = 1.0f, num = 0.0f;
#pragma unroll
    for (int gg = 0; gg < 4; ++gg) {
      if (m & (1 << gg)) {
        const float lv = mls[r * 516 + gg * 128 + 64 + ll];
        const float mu = mls[r * 516 + gg * 128 + ll];
        const float t  = expf(-lv);
        tau += t;
        num = fmaf(t, mu, num);
      }
    }
    const float zv = num / tau + eps[(size_t)(rb + r) * LATD + ll] * rsqrtf(tau);
    zbp[(ll >> 5) * 512 + (r * 4 + ((ll >> 3) & 3)) * 8 + (ll & 7)] = f2b(zv);
  }
  __syncthreads();

  // dec1: wave g -> cols g*64 + ni*16 + l15 (ni 0..3), K=64 (verified)
  float4_t a3[4];
#pragma unroll
  for (int j = 0; j < 4; ++j) a3[j] = (float4_t){0.f, 0.f, 0.f, 0.f};
  {
    const unsigned short* bb = W3p + (size_t)g * 4096 + lofs;
#pragma unroll
    for (int ks = 0; ks < 2; ++ks) {
      const short8_t af = *(const short8_t*)&zbp[ks * 512 + lofs];
#pragma unroll
      for (int ni = 0; ni < 4; ++ni) {
        const short8_t bf = *(const short8_t*)(bb + ks * 2048 + ni * 512);
        a3[ni] = __builtin_amdgcn_mfma_f32_16x16x32_bf16(af, bf, a3[ni], 0, 0, 0);
      }
    }
  }
#pragma unroll
  for (int ni = 0; ni < 4; ++ni) {
    const int col = g * 64 + ni * 16 + l15;
    const float b = DB1[col];
#pragma unroll
    for (int j = 0; j < 4; ++j)
      Hd[(size_t)(rb + oct * 4 + j) * 256 + col] = f2b(fmaxf(a3[ni][j] + b, 0.0f));
  }
}

// ---------------- dec2: panel-B MFMA + coalesced epilogue (verified) -------
__global__ __launch_bounds__(512) void k_dec2(const unsigned short* __restrict__ Hd,
                                              const unsigned short* __restrict__ W4p,
                                              const float* __restrict__ Bb,
                                              float* __restrict__ Out) {
  __shared__ float obuf[32][264];

  const int tid = threadIdx.x;
  const int w   = tid >> 6;
  const int l   = tid & 63;
  const int g   = w >> 1;
  const int oh  = w & 1;
  const int r0  = blockIdx.x * 32;
  const int ob  = blockIdx.y * 64;
  const int l15 = l & 15;
  const int oct = l >> 4;
  const int lofs = (l15 * 4 + oct) * 8;

  float4_t acc[2][2];
#pragma unroll
  for (int i = 0; i < 2; ++i)
#pragma unroll
    for (int j = 0; j < 2; ++j) acc[i][j] = (float4_t){0.f, 0.f, 0.f, 0.f};

  const unsigned short* bb4 = W4p + ((g * 16 + blockIdx.y) * 2 + oh) * 2048 + lofs;

#pragma unroll
  for (int ks = 0; ks < 2; ++ks) {
    short8_t af[2], bf[2];
#pragma unroll
    for (int mi = 0; mi < 2; ++mi)
      af[mi] = *(const short8_t*)(Hd + (size_t)(r0 + mi * 16 + l15) * 256 +
                                  g * 64 + ks * 32 + oct * 8);
#pragma unroll
    for (int ni = 0; ni < 2; ++ni)
      bf[ni] = *(const short8_t*)(bb4 + ks * 1024 + ni * 512);
#pragma unroll
    for (int mi = 0; mi < 2; ++mi)
#pragma unroll
      for (int ni = 0; ni < 2; ++ni)
        acc[mi][ni] = __builtin_amdgcn_mfma_f32_16x16x32_bf16(af[mi], bf[ni], acc[mi][ni], 0, 0, 0);
  }

#pragma unroll
  for (int ni = 0; ni < 2; ++ni) {
    const int lo = oh * 32 + ni * 16 + l15;
    const float b = Bb[g * 1024 + ob + lo];
#pragma unroll
    for (int mi = 0; mi < 2; ++mi) {
      const int rloc = mi * 16 + oct * 4;
#pragma unroll
      for (int j = 0; j < 4; ++j)
        obuf[rloc + j][4 * lo + g] = acc[mi][ni][j] + b;
    }
  }
  __syncthreads();

#pragma unroll
  for (int i = 0; i < 4; ++i) {
    const int q = tid + i * 512;
    const int row = q >> 6, c4 = q & 63;
    const float4 v = *(const float4*)&obuf[row][c4 * 4];
    *(float4*)(Out + (size_t)(r0 + row) * OBS + 4 * ob + c4 * 4) = v;
  }
}

extern "C" void kernel_launch(void* const* d_in, const int* in_sizes, int n_in,
                              void* d_out, int out_size, void* d_ws, size_t ws_size,
                              hipStream_t stream) {
  const float* X          = (const float*)d_in[0];
  const float* eps        = (const float*)d_in[1];
  const int*   subset_idx = (const int*)  d_in[2];
  const float* enc_w1     = (const float*)d_in[3];
  const float* enc_b1     = (const float*)d_in[4];
  const float* enc_w2     = (const float*)d_in[5];
  const float* enc_b2     = (const float*)d_in[6];
  const float* dec_w1     = (const float*)d_in[7];
  const float* dec_b1     = (const float*)d_in[8];
  const float* dec_w2     = (const float*)d_in[9];
  const float* dec_b2     = (const float*)d_in[10];
  float* out = (float*)d_out;

  char* wsb = (char*)d_ws;
  unsigned short* Xt   = (unsigned short*)wsb;                                // 64 MB
  unsigned short* Hrow = (unsigned short*)(wsb + (64u << 20));                // 8 MB
  unsigned short* Hd   = (unsigned short*)(wsb + (72u << 20));                // 4 MB
  unsigned short* W1p  = (unsigned short*)(wsb + (76u << 20));                // 1 MB
  unsigned short* W2p  = (unsigned short*)(wsb + (77u << 20));                // 128 KB
  unsigned short* W3p  = (unsigned short*)(wsb + (77u << 20) + (128u << 10)); // 32 KB
  unsigned short* W4p  = (unsigned short*)(wsb + (77u << 20) + (160u << 10)); // 512 KB

  k_prep0<<<5792, 512, 0, stream>>>(enc_w1, enc_w2, dec_w1, dec_w2, X,
                                    W1p, W2p, W3p, W4p, Xt);
  k_enc1c<<<dim3(64, 4, 2), 512, 0, stream>>>(Xt, W1p, enc_b1, Hrow);
  k_samp4<<<512, 256, 0, stream>>>(Hrow, W2p, W3p, enc_b2, dec_b1,
                                   eps, subset_idx, Hd);
  k_dec2<<<dim3(256, 16), 512, 0, stream>>>(Hd, W4p, dec_b2, out);
}